// Round 4
// baseline (834.138 us; speedup 1.0000x reference)
//
#include <hip/hip_runtime.h>

#define N_NODES 500000
#define N_EDGES 5000000

// ---------------------------------------------------------------------------
// Pass 1: in-degree (real edges only; self-loop added as +1 later).
// dst-only read: 20 MB. Vectorized int4 loads (4 edges/thread/iter).
// ---------------------------------------------------------------------------
__global__ __launch_bounds__(256)
void deg_kernel(const int* __restrict__ dst, float* __restrict__ deg) {
    const int tid = blockIdx.x * blockDim.x + threadIdx.x;
    const int stride = gridDim.x * blockDim.x;
    const int nvec = N_EDGES / 4;  // 5,000,000 / 4 = 1,250,000 exact
    const int4* dst4 = (const int4*)dst;
    for (int i = tid; i < nvec; i += stride) {
        int4 d = dst4[i];
        atomicAdd(&deg[d.x], 1.0f);
        atomicAdd(&deg[d.y], 1.0f);
        atomicAdd(&deg[d.z], 1.0f);
        atomicAdd(&deg[d.w], 1.0f);
    }
}

// ---------------------------------------------------------------------------
// Pass 2: dinv = rsqrt(deg + 1)  (self-loop => deg >= 1 always, matches
// reference's where(deg>0, rsqrt(max(deg,1)), 0));  u = x * dinv.
// dinv written in place over deg.
// ---------------------------------------------------------------------------
__global__ __launch_bounds__(256)
void node1_kernel(const float* __restrict__ x,
                  float* __restrict__ deg_to_dinv,
                  float* __restrict__ u) {
    const int i = blockIdx.x * blockDim.x + threadIdx.x;
    if (i >= N_NODES) return;
    float di = rsqrtf(deg_to_dinv[i] + 1.0f);
    deg_to_dinv[i] = di;
    u[i] = x[i] * di;
}

// ---------------------------------------------------------------------------
// Scatter pass (used twice): acc[dst] += val[src].
// src+dst reads: 40 MB. Gathers/atomics hit the 2 MB node arrays (cache-res).
// ---------------------------------------------------------------------------
__global__ __launch_bounds__(256)
void scatter_kernel(const int* __restrict__ src,
                    const int* __restrict__ dst,
                    const float* __restrict__ val,
                    float* __restrict__ acc) {
    const int tid = blockIdx.x * blockDim.x + threadIdx.x;
    const int stride = gridDim.x * blockDim.x;
    const int nvec = N_EDGES / 4;
    const int4* src4 = (const int4*)src;
    const int4* dst4 = (const int4*)dst;
    for (int i = tid; i < nvec; i += stride) {
        int4 s = src4[i];
        int4 d = dst4[i];
        float vx = val[s.x];
        float vy = val[s.y];
        float vz = val[s.z];
        float vw = val[s.w];
        atomicAdd(&acc[d.x], vx);
        atomicAdd(&acc[d.y], vy);
        atomicAdd(&acc[d.z], vz);
        atomicAdd(&acc[d.w], vw);
    }
}

// ---------------------------------------------------------------------------
// Pass 4: collapse the 16-wide MLP per node.
// s = dinv*(acc1 + u);  t = sum_j relu(W1[j]*s + b1[j]) * W2[j];  w = t*dinv.
// W1/b1/W2 are uniform-address loads -> cached scalar reads.
// ---------------------------------------------------------------------------
__global__ __launch_bounds__(256)
void node2_kernel(const float* __restrict__ dinv,
                  const float* __restrict__ u,
                  const float* __restrict__ acc1,
                  const float* __restrict__ W1,
                  const float* __restrict__ b1,
                  const float* __restrict__ W2,
                  float* __restrict__ w) {
    const int i = blockIdx.x * blockDim.x + threadIdx.x;
    if (i >= N_NODES) return;
    float di = dinv[i];
    float s = di * (acc1[i] + u[i]);
    float t = 0.0f;
#pragma unroll
    for (int j = 0; j < 16; ++j) {
        float h = fmaf(W1[j], s, b1[j]);
        h = fmaxf(h, 0.0f);
        t = fmaf(h, W2[j], t);
    }
    w[i] = t * di;
}

// ---------------------------------------------------------------------------
// Pass 6: out = dinv*(acc2 + w) + b2
// (w may alias out: per-thread read w[i] happens before the out[i] write).
// ---------------------------------------------------------------------------
__global__ __launch_bounds__(256)
void final_kernel(const float* __restrict__ dinv,
                  const float* __restrict__ w,
                  const float* __restrict__ acc2,
                  const float* __restrict__ b2,
                  float* __restrict__ out) {
    const int i = blockIdx.x * blockDim.x + threadIdx.x;
    if (i >= N_NODES) return;
    float wi = w[i];
    out[i] = fmaf(dinv[i], acc2[i] + wi, b2[0]);
}

extern "C" void kernel_launch(void* const* d_in, const int* in_sizes, int n_in,
                              void* d_out, int out_size, void* d_ws, size_t ws_size,
                              hipStream_t stream) {
    const float* x  = (const float*)d_in[0];
    const float* W1 = (const float*)d_in[1];
    const float* b1 = (const float*)d_in[2];
    const float* W2 = (const float*)d_in[3];
    const float* b2 = (const float*)d_in[4];
    const int* edge_index = (const int*)d_in[5];
    const int* src = edge_index;             // edge_index[0, :]
    const int* dst = edge_index + N_EDGES;   // edge_index[1, :]
    float* out = (float*)d_out;

    float* buf  = (float*)d_ws;
    float* dinv = buf;                 // deg, then dinv in place
    float* acc1 = buf + 1 * N_NODES;
    float* acc2 = buf + 2 * N_NODES;
    float* u    = buf + 3 * N_NODES;
    float* w    = out;                 // aliased: node2 writes, final reads+overwrites

    // d_ws is re-poisoned to 0xAA before every timed call: zero the three
    // accumulator arrays (deg, acc1, acc2) each launch.
    hipMemsetAsync(d_ws, 0, 3 * N_NODES * sizeof(float), stream);

    const int nodeBlocks = (N_NODES + 255) / 256;
    const int edgeBlocks = 2048;  // grid-stride over 1.25M int4 edge packets

    deg_kernel<<<edgeBlocks, 256, 0, stream>>>(dst, dinv);
    node1_kernel<<<nodeBlocks, 256, 0, stream>>>(x, dinv, u);
    scatter_kernel<<<edgeBlocks, 256, 0, stream>>>(src, dst, u, acc1);
    node2_kernel<<<nodeBlocks, 256, 0, stream>>>(dinv, u, acc1, W1, b1, W2, w);
    scatter_kernel<<<edgeBlocks, 256, 0, stream>>>(src, dst, w, acc2);
    final_kernel<<<nodeBlocks, 256, 0, stream>>>(dinv, w, acc2, b2, out);
}

// Round 6
// 235.042 us; speedup vs baseline: 3.5489x; 3.5489x over previous
//
#include <hip/hip_runtime.h>

#define N_NODES 500000
#define N_EDGES 5000000
#define NB 1954           // ceil(N_NODES/256) buckets of 256 nodes
#define PB 512            // partition blocks for hist/place
#define EPB 9768          // edges per partition block (mult of 8; PB*EPB >= N_EDGES)

// ===========================================================================
// FAST PATH: zero global atomics. Bucket-sort edges by dst>>8, aggregate in LDS.
// ===========================================================================

// K1: per-block histogram of dst buckets. hist[block][bin], coalesced row write.
__global__ __launch_bounds__(256)
void hist_kernel(const int* __restrict__ dst, unsigned* __restrict__ hist) {
    __shared__ unsigned h[NB];
    for (int i = threadIdx.x; i < NB; i += 256) h[i] = 0u;
    __syncthreads();
    const int b = blockIdx.x;
    const long s0 = (long)b * EPB;
    const int n = (int)min((long)EPB, (long)N_EDGES - s0);
    const int4* d4 = (const int4*)(dst + s0);
    const int n4 = n >> 2;  // n is always a multiple of 4
    for (int i = threadIdx.x; i < n4; i += 256) {
        int4 d = d4[i];
        atomicAdd(&h[d.x >> 8], 1u);
        atomicAdd(&h[d.y >> 8], 1u);
        atomicAdd(&h[d.z >> 8], 1u);
        atomicAdd(&h[d.w >> 8], 1u);
    }
    __syncthreads();
    unsigned* row = hist + (size_t)b * NB;
    for (int i = threadIdx.x; i < NB; i += 256) row[i] = h[i];
}

// K2: per-bin exclusive prefix over the PB block counts (in place) + bin total.
__global__ __launch_bounds__(512)
void prefix_kernel(unsigned* __restrict__ hist, unsigned* __restrict__ binTotal) {
    __shared__ unsigned A[PB], B[PB];
    const int bin = blockIdx.x;
    const int t = threadIdx.x;
    const unsigned c = hist[(size_t)t * NB + bin];
    A[t] = c;
    __syncthreads();
    unsigned* cur = A; unsigned* nxt = B;
    for (int off = 1; off < PB; off <<= 1) {
        nxt[t] = cur[t] + (t >= off ? cur[t - off] : 0u);
        __syncthreads();
        unsigned* tmp = cur; cur = nxt; nxt = tmp;
    }
    hist[(size_t)t * NB + bin] = cur[t] - c;      // exclusive prefix
    if (t == PB - 1) binTotal[bin] = cur[PB - 1]; // total for this bin
}

// K2b: exclusive scan of the NB bin totals -> binStart[0..NB] (binStart[NB]=E).
__global__ __launch_bounds__(1024)
void binscan_kernel(const unsigned* __restrict__ binTotal,
                    unsigned* __restrict__ binStart) {
    __shared__ unsigned A[2048], B[2048];
    const int t = threadIdx.x;
    for (int k = 0; k < 2; ++k) {
        int i = t + k * 1024;
        A[i] = (i < NB) ? binTotal[i] : 0u;
    }
    __syncthreads();
    unsigned* cur = A; unsigned* nxt = B;
    for (int off = 1; off < 2048; off <<= 1) {
        for (int k = 0; k < 2; ++k) {
            int i = t + k * 1024;
            nxt[i] = cur[i] + (i >= off ? cur[i - off] : 0u);
        }
        __syncthreads();
        unsigned* tmp = cur; cur = nxt; nxt = tmp;
    }
    for (int k = 0; k < 2; ++k) {
        int i = t + k * 1024;
        if (i < NB) binStart[i] = (i == 0) ? 0u : cur[i - 1];
    }
    if (t == 0) binStart[NB] = cur[NB - 1];
}

// K3: place each edge into its bucket region: rec = (dstLocal<<24) | src.
// Ranks from LDS counters seeded with binStart[bin] + hist[block][bin].
__global__ __launch_bounds__(256)
void place_kernel(const int* __restrict__ src, const int* __restrict__ dst,
                  const unsigned* __restrict__ hist,
                  const unsigned* __restrict__ binStart,
                  unsigned* __restrict__ edgebuf) {
    __shared__ unsigned base[NB];
    const int b = blockIdx.x;
    const unsigned* row = hist + (size_t)b * NB;
    for (int i = threadIdx.x; i < NB; i += 256) base[i] = binStart[i] + row[i];
    __syncthreads();
    const long s0 = (long)b * EPB;
    const int n = (int)min((long)EPB, (long)N_EDGES - s0);
    const int4* s4 = (const int4*)(src + s0);
    const int4* d4 = (const int4*)(dst + s0);
    const int n4 = n >> 2;
    for (int i = threadIdx.x; i < n4; i += 256) {
        int4 s = s4[i];
        int4 d = d4[i];
        unsigned p;
        p = atomicAdd(&base[d.x >> 8], 1u);
        edgebuf[p] = ((unsigned)(d.x & 255) << 24) | (unsigned)s.x;
        p = atomicAdd(&base[d.y >> 8], 1u);
        edgebuf[p] = ((unsigned)(d.y & 255) << 24) | (unsigned)s.y;
        p = atomicAdd(&base[d.z >> 8], 1u);
        edgebuf[p] = ((unsigned)(d.z & 255) << 24) | (unsigned)s.z;
        p = atomicAdd(&base[d.w >> 8], 1u);
        edgebuf[p] = ((unsigned)(d.w & 255) << 24) | (unsigned)s.w;
    }
}

// K4a: per-bucket in-degree count -> dinv = rsqrt(deg+1); u = x*dinv. (node1 fused)
__global__ __launch_bounds__(256)
void deg_dinv_kernel(const unsigned* __restrict__ edgebuf,
                     const unsigned* __restrict__ binStart,
                     const float* __restrict__ x,
                     float* __restrict__ dinv, float* __restrict__ u) {
    __shared__ unsigned cnt[256];
    cnt[threadIdx.x] = 0u;
    __syncthreads();
    const int bin = blockIdx.x;
    const unsigned e0 = binStart[bin], e1 = binStart[bin + 1];
    for (unsigned e = e0 + threadIdx.x; e < e1; e += 256)
        atomicAdd(&cnt[edgebuf[e] >> 24], 1u);
    __syncthreads();
    const int node = (bin << 8) + threadIdx.x;
    if (node < N_NODES) {
        float di = rsqrtf((float)cnt[threadIdx.x] + 1.0f);
        dinv[node] = di;
        u[node] = x[node] * di;
    }
}

// K4b: agg1 (sum u[src] per node, LDS) + collapsed 16-wide MLP -> w. (node2 fused)
__global__ __launch_bounds__(256)
void agg1_kernel(const unsigned* __restrict__ edgebuf,
                 const unsigned* __restrict__ binStart,
                 const float* __restrict__ dinv, const float* __restrict__ u,
                 const float* __restrict__ W1, const float* __restrict__ b1,
                 const float* __restrict__ W2, float* __restrict__ w) {
    __shared__ float sum[256];
    sum[threadIdx.x] = 0.0f;
    __syncthreads();
    const int bin = blockIdx.x;
    const unsigned e0 = binStart[bin], e1 = binStart[bin + 1];
    for (unsigned e = e0 + threadIdx.x; e < e1; e += 256) {
        unsigned rec = edgebuf[e];
        float v = u[rec & 0xFFFFFFu];  // src in low 24 bits (19 used)
        atomicAdd(&sum[rec >> 24], v);
    }
    __syncthreads();
    const int node = (bin << 8) + threadIdx.x;
    if (node < N_NODES) {
        float di = dinv[node];
        float s = di * (sum[threadIdx.x] + u[node]);
        float t = 0.0f;
#pragma unroll
        for (int j = 0; j < 16; ++j) {
            float h = fmaf(W1[j], s, b1[j]);
            h = fmaxf(h, 0.0f);
            t = fmaf(h, W2[j], t);
        }
        w[node] = t * di;
    }
}

// K4c: agg2 (sum w[src] per node, LDS) + final epilogue -> out.
__global__ __launch_bounds__(256)
void agg2_kernel(const unsigned* __restrict__ edgebuf,
                 const unsigned* __restrict__ binStart,
                 const float* __restrict__ dinv, const float* __restrict__ w,
                 const float* __restrict__ b2, float* __restrict__ out) {
    __shared__ float sum[256];
    sum[threadIdx.x] = 0.0f;
    __syncthreads();
    const int bin = blockIdx.x;
    const unsigned e0 = binStart[bin], e1 = binStart[bin + 1];
    for (unsigned e = e0 + threadIdx.x; e < e1; e += 256) {
        unsigned rec = edgebuf[e];
        atomicAdd(&sum[rec >> 24], w[rec & 0xFFFFFFu]);
    }
    __syncthreads();
    const int node = (bin << 8) + threadIdx.x;
    if (node < N_NODES)
        out[node] = fmaf(dinv[node], sum[threadIdx.x] + w[node], b2[0]);
}

// ===========================================================================
// FALLBACK PATH (verified round-4 kernels) — used only if ws_size is too small.
// ===========================================================================
__global__ __launch_bounds__(256)
void deg_kernel(const int* __restrict__ dst, float* __restrict__ deg) {
    const int tid = blockIdx.x * blockDim.x + threadIdx.x;
    const int stride = gridDim.x * blockDim.x;
    const int nvec = N_EDGES / 4;
    const int4* dst4 = (const int4*)dst;
    for (int i = tid; i < nvec; i += stride) {
        int4 d = dst4[i];
        atomicAdd(&deg[d.x], 1.0f);
        atomicAdd(&deg[d.y], 1.0f);
        atomicAdd(&deg[d.z], 1.0f);
        atomicAdd(&deg[d.w], 1.0f);
    }
}
__global__ __launch_bounds__(256)
void node1_kernel(const float* __restrict__ x, float* __restrict__ deg_to_dinv,
                  float* __restrict__ u) {
    const int i = blockIdx.x * blockDim.x + threadIdx.x;
    if (i >= N_NODES) return;
    float di = rsqrtf(deg_to_dinv[i] + 1.0f);
    deg_to_dinv[i] = di;
    u[i] = x[i] * di;
}
__global__ __launch_bounds__(256)
void scatter_kernel(const int* __restrict__ src, const int* __restrict__ dst,
                    const float* __restrict__ val, float* __restrict__ acc) {
    const int tid = blockIdx.x * blockDim.x + threadIdx.x;
    const int stride = gridDim.x * blockDim.x;
    const int nvec = N_EDGES / 4;
    const int4* src4 = (const int4*)src;
    const int4* dst4 = (const int4*)dst;
    for (int i = tid; i < nvec; i += stride) {
        int4 s = src4[i];
        int4 d = dst4[i];
        atomicAdd(&acc[d.x], val[s.x]);
        atomicAdd(&acc[d.y], val[s.y]);
        atomicAdd(&acc[d.z], val[s.z]);
        atomicAdd(&acc[d.w], val[s.w]);
    }
}
__global__ __launch_bounds__(256)
void node2_kernel(const float* __restrict__ dinv, const float* __restrict__ u,
                  const float* __restrict__ acc1, const float* __restrict__ W1,
                  const float* __restrict__ b1, const float* __restrict__ W2,
                  float* __restrict__ w) {
    const int i = blockIdx.x * blockDim.x + threadIdx.x;
    if (i >= N_NODES) return;
    float di = dinv[i];
    float s = di * (acc1[i] + u[i]);
    float t = 0.0f;
#pragma unroll
    for (int j = 0; j < 16; ++j) {
        float h = fmaf(W1[j], s, b1[j]);
        h = fmaxf(h, 0.0f);
        t = fmaf(h, W2[j], t);
    }
    w[i] = t * di;
}
__global__ __launch_bounds__(256)
void final_kernel(const float* __restrict__ dinv, const float* __restrict__ w,
                  const float* __restrict__ acc2, const float* __restrict__ b2,
                  float* __restrict__ out) {
    const int i = blockIdx.x * blockDim.x + threadIdx.x;
    if (i >= N_NODES) return;
    float wi = w[i];
    out[i] = fmaf(dinv[i], acc2[i] + wi, b2[0]);
}

// ===========================================================================
extern "C" void kernel_launch(void* const* d_in, const int* in_sizes, int n_in,
                              void* d_out, int out_size, void* d_ws, size_t ws_size,
                              hipStream_t stream) {
    const float* x  = (const float*)d_in[0];
    const float* W1 = (const float*)d_in[1];
    const float* b1 = (const float*)d_in[2];
    const float* W2 = (const float*)d_in[3];
    const float* b2 = (const float*)d_in[4];
    const int* edge_index = (const int*)d_in[5];
    const int* src = edge_index;
    const int* dst = edge_index + N_EDGES;
    float* out = (float*)d_out;
    char* ws = (char*)d_ws;

    // Fast-path workspace layout (byte offsets, all 16B-aligned):
    const size_t OFF_EDGEBUF  = 0;                         // u32[N_EDGES]   20,000,000
    const size_t OFF_HIST     = 20000000;                  // u32[PB*NB]      4,001,792
    const size_t OFF_BINSTART = 24009616;                  // u32[NB+1]           7,820
    const size_t OFF_BINTOTAL = 24017440;                  // u32[NB]             7,816
    const size_t OFF_DINV     = 24025280;                  // f32[N] (16B-aligned)
    const size_t OFF_U        = OFF_DINV + 2000000;
    const size_t OFF_W        = OFF_U + 2000000;
    const size_t FAST_WS      = OFF_W + 2000000;

    if (ws_size >= FAST_WS) {
        unsigned* edgebuf  = (unsigned*)(ws + OFF_EDGEBUF);
        unsigned* hist     = (unsigned*)(ws + OFF_HIST);
        unsigned* binStart = (unsigned*)(ws + OFF_BINSTART);
        unsigned* binTotal = (unsigned*)(ws + OFF_BINTOTAL);
        float* dinv = (float*)(ws + OFF_DINV);
        float* u    = (float*)(ws + OFF_U);
        float* w    = (float*)(ws + OFF_W);

        hist_kernel<<<PB, 256, 0, stream>>>(dst, hist);
        prefix_kernel<<<NB, PB, 0, stream>>>(hist, binTotal);
        binscan_kernel<<<1, 1024, 0, stream>>>(binTotal, binStart);
        place_kernel<<<PB, 256, 0, stream>>>(src, dst, hist, binStart, edgebuf);
        deg_dinv_kernel<<<NB, 256, 0, stream>>>(edgebuf, binStart, x, dinv, u);
        agg1_kernel<<<NB, 256, 0, stream>>>(edgebuf, binStart, dinv, u, W1, b1, W2, w);
        agg2_kernel<<<NB, 256, 0, stream>>>(edgebuf, binStart, dinv, w, b2, out);
    } else {
        // Fallback: verified global-atomic path.
        float* buf  = (float*)d_ws;
        float* dinv = buf;
        float* acc1 = buf + 1 * N_NODES;
        float* acc2 = buf + 2 * N_NODES;
        float* u    = buf + 3 * N_NODES;
        float* w    = out;
        hipMemsetAsync(d_ws, 0, 3 * N_NODES * sizeof(float), stream);
        const int nodeBlocks = (N_NODES + 255) / 256;
        const int edgeBlocks = 2048;
        deg_kernel<<<edgeBlocks, 256, 0, stream>>>(dst, dinv);
        node1_kernel<<<nodeBlocks, 256, 0, stream>>>(x, dinv, u);
        scatter_kernel<<<edgeBlocks, 256, 0, stream>>>(src, dst, u, acc1);
        node2_kernel<<<nodeBlocks, 256, 0, stream>>>(dinv, u, acc1, W1, b1, W2, w);
        scatter_kernel<<<edgeBlocks, 256, 0, stream>>>(src, dst, w, acc2);
        final_kernel<<<nodeBlocks, 256, 0, stream>>>(dinv, w, acc2, b2, out);
    }
}

// Round 12
// 206.181 us; speedup vs baseline: 4.0457x; 1.1400x over previous
//
#include <hip/hip_runtime.h>

#define N_NODES 500000
#define N_EDGES 5000000
#define NB_C 489          // ceil(N_NODES/1024) buckets of 1024 nodes (dst>>10)
#define PB 512            // partition blocks for hist/place
#define EPB 9768          // edges per partition block (mult of 4; PB*EPB >= N_EDGES)
#define SRC_MASK 0xFFFFFu // low 20 bits = src (src < 2^19)

// ===========================================================================
// FAST PATH: zero global atomics. Bucket-sort edges by dst>>10, aggregate in LDS.
// Bucket = 1024 nodes: per-block run per bin ~20 recs (80B) => low write ampl.
// ===========================================================================

// K1: per-block histogram of dst buckets. hist[block][bin], coalesced row write.
__global__ __launch_bounds__(512)
void hist_kernel(const int* __restrict__ dst, unsigned* __restrict__ hist) {
    __shared__ unsigned h[NB_C];
    for (int i = threadIdx.x; i < NB_C; i += 512) h[i] = 0u;
    __syncthreads();
    const int b = blockIdx.x;
    const long s0 = (long)b * EPB;
    const int n = (int)min((long)EPB, (long)N_EDGES - s0);
    const int4* d4 = (const int4*)(dst + s0);
    const int n4 = n >> 2;  // n always a multiple of 4
    for (int i = threadIdx.x; i < n4; i += 512) {
        int4 d = d4[i];
        atomicAdd(&h[d.x >> 10], 1u);
        atomicAdd(&h[d.y >> 10], 1u);
        atomicAdd(&h[d.z >> 10], 1u);
        atomicAdd(&h[d.w >> 10], 1u);
    }
    __syncthreads();
    unsigned* row = hist + (size_t)b * NB_C;
    for (int i = threadIdx.x; i < NB_C; i += 512) row[i] = h[i];
}

// K2: per-bin exclusive prefix over the PB block counts (in place) + bin total.
__global__ __launch_bounds__(512)
void prefix_kernel(unsigned* __restrict__ hist, unsigned* __restrict__ binTotal) {
    __shared__ unsigned A[PB], B[PB];
    const int bin = blockIdx.x;
    const int t = threadIdx.x;
    const unsigned c = hist[(size_t)t * NB_C + bin];
    A[t] = c;
    __syncthreads();
    unsigned* cur = A; unsigned* nxt = B;
    for (int off = 1; off < PB; off <<= 1) {
        nxt[t] = cur[t] + (t >= off ? cur[t - off] : 0u);
        __syncthreads();
        unsigned* tmp = cur; cur = nxt; nxt = tmp;
    }
    hist[(size_t)t * NB_C + bin] = cur[t] - c;      // exclusive prefix
    if (t == PB - 1) binTotal[bin] = cur[PB - 1];   // total for this bin
}

// K2b: exclusive scan of the NB_C bin totals -> binStart[0..NB_C].
__global__ __launch_bounds__(512)
void binscan_kernel(const unsigned* __restrict__ binTotal,
                    unsigned* __restrict__ binStart) {
    __shared__ unsigned A[512], B[512];
    const int t = threadIdx.x;
    A[t] = (t < NB_C) ? binTotal[t] : 0u;
    __syncthreads();
    unsigned* cur = A; unsigned* nxt = B;
    for (int off = 1; off < 512; off <<= 1) {
        nxt[t] = cur[t] + (t >= off ? cur[t - off] : 0u);
        __syncthreads();
        unsigned* tmp = cur; cur = nxt; nxt = tmp;
    }
    if (t < NB_C) binStart[t] = (t == 0) ? 0u : cur[t - 1];
    if (t == 0) binStart[NB_C] = cur[NB_C - 1];
}

// K3: place each edge into its bucket region: rec = (dstLocal<<20) | src.
__global__ __launch_bounds__(512)
void place_kernel(const int* __restrict__ src, const int* __restrict__ dst,
                  const unsigned* __restrict__ hist,
                  const unsigned* __restrict__ binStart,
                  unsigned* __restrict__ edgebuf) {
    __shared__ unsigned base[NB_C];
    const int b = blockIdx.x;
    const unsigned* row = hist + (size_t)b * NB_C;
    for (int i = threadIdx.x; i < NB_C; i += 512) base[i] = binStart[i] + row[i];
    __syncthreads();
    const long s0 = (long)b * EPB;
    const int n = (int)min((long)EPB, (long)N_EDGES - s0);
    const int4* s4 = (const int4*)(src + s0);
    const int4* d4 = (const int4*)(dst + s0);
    const int n4 = n >> 2;
    for (int i = threadIdx.x; i < n4; i += 512) {
        int4 s = s4[i];
        int4 d = d4[i];
        unsigned p;
        p = atomicAdd(&base[d.x >> 10], 1u);
        edgebuf[p] = ((unsigned)(d.x & 1023) << 20) | (unsigned)s.x;
        p = atomicAdd(&base[d.y >> 10], 1u);
        edgebuf[p] = ((unsigned)(d.y & 1023) << 20) | (unsigned)s.y;
        p = atomicAdd(&base[d.z >> 10], 1u);
        edgebuf[p] = ((unsigned)(d.z & 1023) << 20) | (unsigned)s.z;
        p = atomicAdd(&base[d.w >> 10], 1u);
        edgebuf[p] = ((unsigned)(d.w & 1023) << 20) | (unsigned)s.w;
    }
}

// K4a: per-bucket in-degree -> dinv = rsqrt(deg+1); u = x*dinv. (node1 fused)
__global__ __launch_bounds__(512)
void deg_dinv_kernel(const unsigned* __restrict__ edgebuf,
                     const unsigned* __restrict__ binStart,
                     const float* __restrict__ x,
                     float* __restrict__ dinv, float* __restrict__ u) {
    __shared__ unsigned cnt[1024];
    cnt[threadIdx.x] = 0u;
    cnt[threadIdx.x + 512] = 0u;
    __syncthreads();
    const int bin = blockIdx.x;
    const unsigned e0 = binStart[bin], e1 = binStart[bin + 1];
    // head (to 16B alignment), vector body, tail
    const unsigned ea = (e0 + 3u) & ~3u;
    const unsigned eb = e1 & ~3u;
    for (unsigned e = e0 + threadIdx.x; e < min(ea, e1); e += 512)
        atomicAdd(&cnt[edgebuf[e] >> 20], 1u);
    if (ea < eb) {
        const uint4* p4 = (const uint4*)(edgebuf + ea);
        const unsigned nv = (eb - ea) >> 2;
        for (unsigned i = threadIdx.x; i < nv; i += 512) {
            uint4 r = p4[i];
            atomicAdd(&cnt[r.x >> 20], 1u);
            atomicAdd(&cnt[r.y >> 20], 1u);
            atomicAdd(&cnt[r.z >> 20], 1u);
            atomicAdd(&cnt[r.w >> 20], 1u);
        }
    }
    for (unsigned e = max(eb, min(ea, e1)) + threadIdx.x; e < e1; e += 512)
        atomicAdd(&cnt[edgebuf[e] >> 20], 1u);
    __syncthreads();
#pragma unroll
    for (int k = 0; k < 2; ++k) {
        const int slot = threadIdx.x + k * 512;
        const int node = (bin << 10) + slot;
        if (node < N_NODES) {
            float di = rsqrtf((float)cnt[slot] + 1.0f);
            dinv[node] = di;
            u[node] = x[node] * di;
        }
    }
}

// K4b: agg1 (sum u[src] per node, LDS) + collapsed 16-wide MLP -> w. (node2 fused)
__global__ __launch_bounds__(512)
void agg1_kernel(const unsigned* __restrict__ edgebuf,
                 const unsigned* __restrict__ binStart,
                 const float* __restrict__ dinv, const float* __restrict__ u,
                 const float* __restrict__ W1, const float* __restrict__ b1,
                 const float* __restrict__ W2, float* __restrict__ w) {
    __shared__ float sum[1024];
    sum[threadIdx.x] = 0.0f;
    sum[threadIdx.x + 512] = 0.0f;
    __syncthreads();
    const int bin = blockIdx.x;
    const unsigned e0 = binStart[bin], e1 = binStart[bin + 1];
    const unsigned ea = (e0 + 3u) & ~3u;
    const unsigned eb = e1 & ~3u;
    for (unsigned e = e0 + threadIdx.x; e < min(ea, e1); e += 512) {
        unsigned rec = edgebuf[e];
        atomicAdd(&sum[rec >> 20], u[rec & SRC_MASK]);
    }
    if (ea < eb) {
        const uint4* p4 = (const uint4*)(edgebuf + ea);
        const unsigned nv = (eb - ea) >> 2;
        for (unsigned i = threadIdx.x; i < nv; i += 512) {
            uint4 r = p4[i];
            atomicAdd(&sum[r.x >> 20], u[r.x & SRC_MASK]);
            atomicAdd(&sum[r.y >> 20], u[r.y & SRC_MASK]);
            atomicAdd(&sum[r.z >> 20], u[r.z & SRC_MASK]);
            atomicAdd(&sum[r.w >> 20], u[r.w & SRC_MASK]);
        }
    }
    for (unsigned e = max(eb, min(ea, e1)) + threadIdx.x; e < e1; e += 512) {
        unsigned rec = edgebuf[e];
        atomicAdd(&sum[rec >> 20], u[rec & SRC_MASK]);
    }
    __syncthreads();
#pragma unroll
    for (int k = 0; k < 2; ++k) {
        const int slot = threadIdx.x + k * 512;
        const int node = (bin << 10) + slot;
        if (node < N_NODES) {
            float di = dinv[node];
            float s = di * (sum[slot] + u[node]);
            float t = 0.0f;
#pragma unroll
            for (int j = 0; j < 16; ++j) {
                float h = fmaf(W1[j], s, b1[j]);
                h = fmaxf(h, 0.0f);
                t = fmaf(h, W2[j], t);
            }
            w[node] = t * di;
        }
    }
}

// K4c: agg2 (sum w[src] per node, LDS) + final epilogue -> out.
__global__ __launch_bounds__(512)
void agg2_kernel(const unsigned* __restrict__ edgebuf,
                 const unsigned* __restrict__ binStart,
                 const float* __restrict__ dinv, const float* __restrict__ w,
                 const float* __restrict__ b2, float* __restrict__ out) {
    __shared__ float sum[1024];
    sum[threadIdx.x] = 0.0f;
    sum[threadIdx.x + 512] = 0.0f;
    __syncthreads();
    const int bin = blockIdx.x;
    const unsigned e0 = binStart[bin], e1 = binStart[bin + 1];
    const unsigned ea = (e0 + 3u) & ~3u;
    const unsigned eb = e1 & ~3u;
    for (unsigned e = e0 + threadIdx.x; e < min(ea, e1); e += 512) {
        unsigned rec = edgebuf[e];
        atomicAdd(&sum[rec >> 20], w[rec & SRC_MASK]);
    }
    if (ea < eb) {
        const uint4* p4 = (const uint4*)(edgebuf + ea);
        const unsigned nv = (eb - ea) >> 2;
        for (unsigned i = threadIdx.x; i < nv; i += 512) {
            uint4 r = p4[i];
            atomicAdd(&sum[r.x >> 20], w[r.x & SRC_MASK]);
            atomicAdd(&sum[r.y >> 20], w[r.y & SRC_MASK]);
            atomicAdd(&sum[r.z >> 20], w[r.z & SRC_MASK]);
            atomicAdd(&sum[r.w >> 20], w[r.w & SRC_MASK]);
        }
    }
    for (unsigned e = max(eb, min(ea, e1)) + threadIdx.x; e < e1; e += 512) {
        unsigned rec = edgebuf[e];
        atomicAdd(&sum[rec >> 20], w[rec & SRC_MASK]);
    }
    __syncthreads();
#pragma unroll
    for (int k = 0; k < 2; ++k) {
        const int slot = threadIdx.x + k * 512;
        const int node = (bin << 10) + slot;
        if (node < N_NODES)
            out[node] = fmaf(dinv[node], sum[slot] + w[node], b2[0]);
    }
}

// ===========================================================================
// FALLBACK PATH (verified round-4 kernels) — used only if ws_size is too small.
// ===========================================================================
__global__ __launch_bounds__(256)
void deg_kernel(const int* __restrict__ dst, float* __restrict__ deg) {
    const int tid = blockIdx.x * blockDim.x + threadIdx.x;
    const int stride = gridDim.x * blockDim.x;
    const int nvec = N_EDGES / 4;
    const int4* dst4 = (const int4*)dst;
    for (int i = tid; i < nvec; i += stride) {
        int4 d = dst4[i];
        atomicAdd(&deg[d.x], 1.0f);
        atomicAdd(&deg[d.y], 1.0f);
        atomicAdd(&deg[d.z], 1.0f);
        atomicAdd(&deg[d.w], 1.0f);
    }
}
__global__ __launch_bounds__(256)
void node1_kernel(const float* __restrict__ x, float* __restrict__ deg_to_dinv,
                  float* __restrict__ u) {
    const int i = blockIdx.x * blockDim.x + threadIdx.x;
    if (i >= N_NODES) return;
    float di = rsqrtf(deg_to_dinv[i] + 1.0f);
    deg_to_dinv[i] = di;
    u[i] = x[i] * di;
}
__global__ __launch_bounds__(256)
void scatter_kernel(const int* __restrict__ src, const int* __restrict__ dst,
                    const float* __restrict__ val, float* __restrict__ acc) {
    const int tid = blockIdx.x * blockDim.x + threadIdx.x;
    const int stride = gridDim.x * blockDim.x;
    const int nvec = N_EDGES / 4;
    const int4* src4 = (const int4*)src;
    const int4* dst4 = (const int4*)dst;
    for (int i = tid; i < nvec; i += stride) {
        int4 s = src4[i];
        int4 d = dst4[i];
        atomicAdd(&acc[d.x], val[s.x]);
        atomicAdd(&acc[d.y], val[s.y]);
        atomicAdd(&acc[d.z], val[s.z]);
        atomicAdd(&acc[d.w], val[s.w]);
    }
}
__global__ __launch_bounds__(256)
void node2_kernel(const float* __restrict__ dinv, const float* __restrict__ u,
                  const float* __restrict__ acc1, const float* __restrict__ W1,
                  const float* __restrict__ b1, const float* __restrict__ W2,
                  float* __restrict__ w) {
    const int i = blockIdx.x * blockDim.x + threadIdx.x;
    if (i >= N_NODES) return;
    float di = dinv[i];
    float s = di * (acc1[i] + u[i]);
    float t = 0.0f;
#pragma unroll
    for (int j = 0; j < 16; ++j) {
        float h = fmaf(W1[j], s, b1[j]);
        h = fmaxf(h, 0.0f);
        t = fmaf(h, W2[j], t);
    }
    w[i] = t * di;
}
__global__ __launch_bounds__(256)
void final_kernel(const float* __restrict__ dinv, const float* __restrict__ w,
                  const float* __restrict__ acc2, const float* __restrict__ b2,
                  float* __restrict__ out) {
    const int i = blockIdx.x * blockDim.x + threadIdx.x;
    if (i >= N_NODES) return;
    float wi = w[i];
    out[i] = fmaf(dinv[i], acc2[i] + wi, b2[0]);
}

// ===========================================================================
extern "C" void kernel_launch(void* const* d_in, const int* in_sizes, int n_in,
                              void* d_out, int out_size, void* d_ws, size_t ws_size,
                              hipStream_t stream) {
    const float* x  = (const float*)d_in[0];
    const float* W1 = (const float*)d_in[1];
    const float* b1 = (const float*)d_in[2];
    const float* W2 = (const float*)d_in[3];
    const float* b2 = (const float*)d_in[4];
    const int* edge_index = (const int*)d_in[5];
    const int* src = edge_index;
    const int* dst = edge_index + N_EDGES;
    float* out = (float*)d_out;
    char* ws = (char*)d_ws;

    // Fast-path workspace layout (byte offsets, 16B-aligned):
    const size_t OFF_EDGEBUF  = 0;                    // u32[N_EDGES]  20,000,000
    const size_t OFF_HIST     = 20000000;             // u32[PB*NB_C]   1,001,472
    const size_t OFF_BINSTART = 21001472;             // u32[NB_C+1]        1,960
    const size_t OFF_BINTOTAL = 21003440;             // u32[NB_C]          1,956
    const size_t OFF_DINV     = 21005408;             // f32[N]
    const size_t OFF_U        = OFF_DINV + 2000000;
    const size_t OFF_W        = OFF_U + 2000000;
    const size_t FAST_WS      = OFF_W + 2000000;      // ~27.0 MB

    if (ws_size >= FAST_WS) {
        unsigned* edgebuf  = (unsigned*)(ws + OFF_EDGEBUF);
        unsigned* hist     = (unsigned*)(ws + OFF_HIST);
        unsigned* binStart = (unsigned*)(ws + OFF_BINSTART);
        unsigned* binTotal = (unsigned*)(ws + OFF_BINTOTAL);
        float* dinv = (float*)(ws + OFF_DINV);
        float* u    = (float*)(ws + OFF_U);
        float* w    = (float*)(ws + OFF_W);

        hist_kernel<<<PB, 512, 0, stream>>>(dst, hist);
        prefix_kernel<<<NB_C, PB, 0, stream>>>(hist, binTotal);
        binscan_kernel<<<1, 512, 0, stream>>>(binTotal, binStart);
        place_kernel<<<PB, 512, 0, stream>>>(src, dst, hist, binStart, edgebuf);
        deg_dinv_kernel<<<NB_C, 512, 0, stream>>>(edgebuf, binStart, x, dinv, u);
        agg1_kernel<<<NB_C, 512, 0, stream>>>(edgebuf, binStart, dinv, u, W1, b1, W2, w);
        agg2_kernel<<<NB_C, 512, 0, stream>>>(edgebuf, binStart, dinv, w, b2, out);
    } else {
        // Fallback: verified global-atomic path.
        float* buf  = (float*)d_ws;
        float* dinv = buf;
        float* acc1 = buf + 1 * N_NODES;
        float* acc2 = buf + 2 * N_NODES;
        float* u    = buf + 3 * N_NODES;
        float* w    = out;
        hipMemsetAsync(d_ws, 0, 3 * N_NODES * sizeof(float), stream);
        const int nodeBlocks = (N_NODES + 255) / 256;
        const int edgeBlocks = 2048;
        deg_kernel<<<edgeBlocks, 256, 0, stream>>>(dst, dinv);
        node1_kernel<<<nodeBlocks, 256, 0, stream>>>(x, dinv, u);
        scatter_kernel<<<edgeBlocks, 256, 0, stream>>>(src, dst, u, acc1);
        node2_kernel<<<nodeBlocks, 256, 0, stream>>>(dinv, u, acc1, W1, b1, W2, w);
        scatter_kernel<<<edgeBlocks, 256, 0, stream>>>(src, dst, w, acc2);
        final_kernel<<<nodeBlocks, 256, 0, stream>>>(dinv, w, acc2, b2, out);
    }
}

// Round 13
// 191.383 us; speedup vs baseline: 4.3585x; 1.0773x over previous
//
#include <hip/hip_runtime.h>

#define N_NODES 500000
#define N_EDGES 5000000
#define NB_C 489          // ceil(N_NODES/1024) buckets of 1024 nodes (dst>>10)
#define PB 512            // partition blocks for hist/place
#define EPB 9768          // edges per partition block (mult of 4; PB*EPB >= N_EDGES)
#define SRC_MASK 0xFFFFFu // low 20 bits = src (src < 2^19)

// ===========================================================================
// FAST PATH: zero global atomics. Bucket-sort edges by dst>>10, aggregate in LDS.
// 1024-thread blocks: ~2 blocks/CU -> ~32 waves/CU (latency-bound kernels).
// ===========================================================================

// K1: per-block histogram of dst buckets. hist[block][bin], coalesced row write.
__global__ __launch_bounds__(1024)
void hist_kernel(const int* __restrict__ dst, unsigned* __restrict__ hist) {
    __shared__ unsigned h[NB_C];
    for (int i = threadIdx.x; i < NB_C; i += 1024) h[i] = 0u;
    __syncthreads();
    const int b = blockIdx.x;
    const long s0 = (long)b * EPB;
    const int n = (int)min((long)EPB, (long)N_EDGES - s0);
    const int4* d4 = (const int4*)(dst + s0);
    const int n4 = n >> 2;  // n always a multiple of 4
    for (int i = threadIdx.x; i < n4; i += 1024) {
        int4 d = d4[i];
        atomicAdd(&h[d.x >> 10], 1u);
        atomicAdd(&h[d.y >> 10], 1u);
        atomicAdd(&h[d.z >> 10], 1u);
        atomicAdd(&h[d.w >> 10], 1u);
    }
    __syncthreads();
    unsigned* row = hist + (size_t)b * NB_C;
    for (int i = threadIdx.x; i < NB_C; i += 1024) row[i] = h[i];
}

// K2: per-bin exclusive prefix over the PB block counts (in place) + bin total.
__global__ __launch_bounds__(512)
void prefix_kernel(unsigned* __restrict__ hist, unsigned* __restrict__ binTotal) {
    __shared__ unsigned A[PB], B[PB];
    const int bin = blockIdx.x;
    const int t = threadIdx.x;
    const unsigned c = hist[(size_t)t * NB_C + bin];
    A[t] = c;
    __syncthreads();
    unsigned* cur = A; unsigned* nxt = B;
    for (int off = 1; off < PB; off <<= 1) {
        nxt[t] = cur[t] + (t >= off ? cur[t - off] : 0u);
        __syncthreads();
        unsigned* tmp = cur; cur = nxt; nxt = tmp;
    }
    hist[(size_t)t * NB_C + bin] = cur[t] - c;      // exclusive prefix
    if (t == PB - 1) binTotal[bin] = cur[PB - 1];   // total for this bin
}

// K2b: exclusive scan of the NB_C bin totals -> binStart[0..NB_C].
__global__ __launch_bounds__(512)
void binscan_kernel(const unsigned* __restrict__ binTotal,
                    unsigned* __restrict__ binStart) {
    __shared__ unsigned A[512], B[512];
    const int t = threadIdx.x;
    A[t] = (t < NB_C) ? binTotal[t] : 0u;
    __syncthreads();
    unsigned* cur = A; unsigned* nxt = B;
    for (int off = 1; off < 512; off <<= 1) {
        nxt[t] = cur[t] + (t >= off ? cur[t - off] : 0u);
        __syncthreads();
        unsigned* tmp = cur; cur = nxt; nxt = tmp;
    }
    if (t < NB_C) binStart[t] = (t == 0) ? 0u : cur[t - 1];
    if (t == 0) binStart[NB_C] = cur[NB_C - 1];
}

// K3: place each edge into its bucket region: rec = (dstLocal<<20) | src.
__global__ __launch_bounds__(1024)
void place_kernel(const int* __restrict__ src, const int* __restrict__ dst,
                  const unsigned* __restrict__ hist,
                  const unsigned* __restrict__ binStart,
                  unsigned* __restrict__ edgebuf) {
    __shared__ unsigned base[NB_C];
    const int b = blockIdx.x;
    const unsigned* row = hist + (size_t)b * NB_C;
    for (int i = threadIdx.x; i < NB_C; i += 1024) base[i] = binStart[i] + row[i];
    __syncthreads();
    const long s0 = (long)b * EPB;
    const int n = (int)min((long)EPB, (long)N_EDGES - s0);
    const int4* s4 = (const int4*)(src + s0);
    const int4* d4 = (const int4*)(dst + s0);
    const int n4 = n >> 2;
    for (int i = threadIdx.x; i < n4; i += 1024) {
        int4 s = s4[i];
        int4 d = d4[i];
        unsigned p;
        p = atomicAdd(&base[d.x >> 10], 1u);
        edgebuf[p] = ((unsigned)(d.x & 1023) << 20) | (unsigned)s.x;
        p = atomicAdd(&base[d.y >> 10], 1u);
        edgebuf[p] = ((unsigned)(d.y & 1023) << 20) | (unsigned)s.y;
        p = atomicAdd(&base[d.z >> 10], 1u);
        edgebuf[p] = ((unsigned)(d.z & 1023) << 20) | (unsigned)s.z;
        p = atomicAdd(&base[d.w >> 10], 1u);
        edgebuf[p] = ((unsigned)(d.w & 1023) << 20) | (unsigned)s.w;
    }
}

// K4a: per-bucket in-degree -> dinv = rsqrt(deg+1); u = x*dinv. (node1 fused)
__global__ __launch_bounds__(1024)
void deg_dinv_kernel(const unsigned* __restrict__ edgebuf,
                     const unsigned* __restrict__ binStart,
                     const float* __restrict__ x,
                     float* __restrict__ dinv, float* __restrict__ u) {
    __shared__ unsigned cnt[1024];
    cnt[threadIdx.x] = 0u;
    __syncthreads();
    const int bin = blockIdx.x;
    const unsigned e0 = binStart[bin], e1 = binStart[bin + 1];
    // head (to 16B alignment), vector body, tail
    const unsigned ea = (e0 + 3u) & ~3u;
    const unsigned eb = e1 & ~3u;
    for (unsigned e = e0 + threadIdx.x; e < min(ea, e1); e += 1024)
        atomicAdd(&cnt[edgebuf[e] >> 20], 1u);
    if (ea < eb) {
        const uint4* p4 = (const uint4*)(edgebuf + ea);
        const unsigned nv = (eb - ea) >> 2;
        for (unsigned i = threadIdx.x; i < nv; i += 1024) {
            uint4 r = p4[i];
            atomicAdd(&cnt[r.x >> 20], 1u);
            atomicAdd(&cnt[r.y >> 20], 1u);
            atomicAdd(&cnt[r.z >> 20], 1u);
            atomicAdd(&cnt[r.w >> 20], 1u);
        }
    }
    for (unsigned e = max(eb, min(ea, e1)) + threadIdx.x; e < e1; e += 1024)
        atomicAdd(&cnt[edgebuf[e] >> 20], 1u);
    __syncthreads();
    const int node = (bin << 10) + threadIdx.x;
    if (node < N_NODES) {
        float di = rsqrtf((float)cnt[threadIdx.x] + 1.0f);
        dinv[node] = di;
        u[node] = x[node] * di;
    }
}

// K4b: agg1 (sum u[src] per node, LDS) + collapsed 16-wide MLP -> w. (node2 fused)
__global__ __launch_bounds__(1024)
void agg1_kernel(const unsigned* __restrict__ edgebuf,
                 const unsigned* __restrict__ binStart,
                 const float* __restrict__ dinv, const float* __restrict__ u,
                 const float* __restrict__ W1, const float* __restrict__ b1,
                 const float* __restrict__ W2, float* __restrict__ w) {
    __shared__ float sum[1024];
    sum[threadIdx.x] = 0.0f;
    __syncthreads();
    const int bin = blockIdx.x;
    const unsigned e0 = binStart[bin], e1 = binStart[bin + 1];
    const unsigned ea = (e0 + 3u) & ~3u;
    const unsigned eb = e1 & ~3u;
    for (unsigned e = e0 + threadIdx.x; e < min(ea, e1); e += 1024) {
        unsigned rec = edgebuf[e];
        atomicAdd(&sum[rec >> 20], u[rec & SRC_MASK]);
    }
    if (ea < eb) {
        const uint4* p4 = (const uint4*)(edgebuf + ea);
        const unsigned nv = (eb - ea) >> 2;
        for (unsigned i = threadIdx.x; i < nv; i += 1024) {
            uint4 r = p4[i];
            atomicAdd(&sum[r.x >> 20], u[r.x & SRC_MASK]);
            atomicAdd(&sum[r.y >> 20], u[r.y & SRC_MASK]);
            atomicAdd(&sum[r.z >> 20], u[r.z & SRC_MASK]);
            atomicAdd(&sum[r.w >> 20], u[r.w & SRC_MASK]);
        }
    }
    for (unsigned e = max(eb, min(ea, e1)) + threadIdx.x; e < e1; e += 1024) {
        unsigned rec = edgebuf[e];
        atomicAdd(&sum[rec >> 20], u[rec & SRC_MASK]);
    }
    __syncthreads();
    const int node = (bin << 10) + threadIdx.x;
    if (node < N_NODES) {
        float di = dinv[node];
        float s = di * (sum[threadIdx.x] + u[node]);
        float t = 0.0f;
#pragma unroll
        for (int j = 0; j < 16; ++j) {
            float h = fmaf(W1[j], s, b1[j]);
            h = fmaxf(h, 0.0f);
            t = fmaf(h, W2[j], t);
        }
        w[node] = t * di;
    }
}

// K4c: agg2 (sum w[src] per node, LDS) + final epilogue -> out.
__global__ __launch_bounds__(1024)
void agg2_kernel(const unsigned* __restrict__ edgebuf,
                 const unsigned* __restrict__ binStart,
                 const float* __restrict__ dinv, const float* __restrict__ w,
                 const float* __restrict__ b2, float* __restrict__ out) {
    __shared__ float sum[1024];
    sum[threadIdx.x] = 0.0f;
    __syncthreads();
    const int bin = blockIdx.x;
    const unsigned e0 = binStart[bin], e1 = binStart[bin + 1];
    const unsigned ea = (e0 + 3u) & ~3u;
    const unsigned eb = e1 & ~3u;
    for (unsigned e = e0 + threadIdx.x; e < min(ea, e1); e += 1024) {
        unsigned rec = edgebuf[e];
        atomicAdd(&sum[rec >> 20], w[rec & SRC_MASK]);
    }
    if (ea < eb) {
        const uint4* p4 = (const uint4*)(edgebuf + ea);
        const unsigned nv = (eb - ea) >> 2;
        for (unsigned i = threadIdx.x; i < nv; i += 1024) {
            uint4 r = p4[i];
            atomicAdd(&sum[r.x >> 20], w[r.x & SRC_MASK]);
            atomicAdd(&sum[r.y >> 20], w[r.y & SRC_MASK]);
            atomicAdd(&sum[r.z >> 20], w[r.z & SRC_MASK]);
            atomicAdd(&sum[r.w >> 20], w[r.w & SRC_MASK]);
        }
    }
    for (unsigned e = max(eb, min(ea, e1)) + threadIdx.x; e < e1; e += 1024) {
        unsigned rec = edgebuf[e];
        atomicAdd(&sum[rec >> 20], w[rec & SRC_MASK]);
    }
    __syncthreads();
    const int node = (bin << 10) + threadIdx.x;
    if (node < N_NODES)
        out[node] = fmaf(dinv[node], sum[threadIdx.x] + w[node], b2[0]);
}

// ===========================================================================
// FALLBACK PATH (verified round-4 kernels) — used only if ws_size is too small.
// ===========================================================================
__global__ __launch_bounds__(256)
void deg_kernel(const int* __restrict__ dst, float* __restrict__ deg) {
    const int tid = blockIdx.x * blockDim.x + threadIdx.x;
    const int stride = gridDim.x * blockDim.x;
    const int nvec = N_EDGES / 4;
    const int4* dst4 = (const int4*)dst;
    for (int i = tid; i < nvec; i += stride) {
        int4 d = dst4[i];
        atomicAdd(&deg[d.x], 1.0f);
        atomicAdd(&deg[d.y], 1.0f);
        atomicAdd(&deg[d.z], 1.0f);
        atomicAdd(&deg[d.w], 1.0f);
    }
}
__global__ __launch_bounds__(256)
void node1_kernel(const float* __restrict__ x, float* __restrict__ deg_to_dinv,
                  float* __restrict__ u) {
    const int i = blockIdx.x * blockDim.x + threadIdx.x;
    if (i >= N_NODES) return;
    float di = rsqrtf(deg_to_dinv[i] + 1.0f);
    deg_to_dinv[i] = di;
    u[i] = x[i] * di;
}
__global__ __launch_bounds__(256)
void scatter_kernel(const int* __restrict__ src, const int* __restrict__ dst,
                    const float* __restrict__ val, float* __restrict__ acc) {
    const int tid = blockIdx.x * blockDim.x + threadIdx.x;
    const int stride = gridDim.x * blockDim.x;
    const int nvec = N_EDGES / 4;
    const int4* src4 = (const int4*)src;
    const int4* dst4 = (const int4*)dst;
    for (int i = tid; i < nvec; i += stride) {
        int4 s = src4[i];
        int4 d = dst4[i];
        atomicAdd(&acc[d.x], val[s.x]);
        atomicAdd(&acc[d.y], val[s.y]);
        atomicAdd(&acc[d.z], val[s.z]);
        atomicAdd(&acc[d.w], val[s.w]);
    }
}
__global__ __launch_bounds__(256)
void node2_kernel(const float* __restrict__ dinv, const float* __restrict__ u,
                  const float* __restrict__ acc1, const float* __restrict__ W1,
                  const float* __restrict__ b1, const float* __restrict__ W2,
                  float* __restrict__ w) {
    const int i = blockIdx.x * blockDim.x + threadIdx.x;
    if (i >= N_NODES) return;
    float di = dinv[i];
    float s = di * (acc1[i] + u[i]);
    float t = 0.0f;
#pragma unroll
    for (int j = 0; j < 16; ++j) {
        float h = fmaf(W1[j], s, b1[j]);
        h = fmaxf(h, 0.0f);
        t = fmaf(h, W2[j], t);
    }
    w[i] = t * di;
}
__global__ __launch_bounds__(256)
void final_kernel(const float* __restrict__ dinv, const float* __restrict__ w,
                  const float* __restrict__ acc2, const float* __restrict__ b2,
                  float* __restrict__ out) {
    const int i = blockIdx.x * blockDim.x + threadIdx.x;
    if (i >= N_NODES) return;
    float wi = w[i];
    out[i] = fmaf(dinv[i], acc2[i] + wi, b2[0]);
}

// ===========================================================================
extern "C" void kernel_launch(void* const* d_in, const int* in_sizes, int n_in,
                              void* d_out, int out_size, void* d_ws, size_t ws_size,
                              hipStream_t stream) {
    const float* x  = (const float*)d_in[0];
    const float* W1 = (const float*)d_in[1];
    const float* b1 = (const float*)d_in[2];
    const float* W2 = (const float*)d_in[3];
    const float* b2 = (const float*)d_in[4];
    const int* edge_index = (const int*)d_in[5];
    const int* src = edge_index;
    const int* dst = edge_index + N_EDGES;
    float* out = (float*)d_out;
    char* ws = (char*)d_ws;

    // Fast-path workspace layout (byte offsets, 16B-aligned):
    const size_t OFF_EDGEBUF  = 0;                    // u32[N_EDGES]  20,000,000
    const size_t OFF_HIST     = 20000000;             // u32[PB*NB_C]   1,001,472
    const size_t OFF_BINSTART = 21001472;             // u32[NB_C+1]        1,960
    const size_t OFF_BINTOTAL = 21003440;             // u32[NB_C]          1,956
    const size_t OFF_DINV     = 21005408;             // f32[N]
    const size_t OFF_U        = OFF_DINV + 2000000;
    const size_t OFF_W        = OFF_U + 2000000;
    const size_t FAST_WS      = OFF_W + 2000000;      // ~27.0 MB

    if (ws_size >= FAST_WS) {
        unsigned* edgebuf  = (unsigned*)(ws + OFF_EDGEBUF);
        unsigned* hist     = (unsigned*)(ws + OFF_HIST);
        unsigned* binStart = (unsigned*)(ws + OFF_BINSTART);
        unsigned* binTotal = (unsigned*)(ws + OFF_BINTOTAL);
        float* dinv = (float*)(ws + OFF_DINV);
        float* u    = (float*)(ws + OFF_U);
        float* w    = (float*)(ws + OFF_W);

        hist_kernel<<<PB, 1024, 0, stream>>>(dst, hist);
        prefix_kernel<<<NB_C, PB, 0, stream>>>(hist, binTotal);
        binscan_kernel<<<1, 512, 0, stream>>>(binTotal, binStart);
        place_kernel<<<PB, 1024, 0, stream>>>(src, dst, hist, binStart, edgebuf);
        deg_dinv_kernel<<<NB_C, 1024, 0, stream>>>(edgebuf, binStart, x, dinv, u);
        agg1_kernel<<<NB_C, 1024, 0, stream>>>(edgebuf, binStart, dinv, u, W1, b1, W2, w);
        agg2_kernel<<<NB_C, 1024, 0, stream>>>(edgebuf, binStart, dinv, w, b2, out);
    } else {
        // Fallback: verified global-atomic path.
        float* buf  = (float*)d_ws;
        float* dinv = buf;
        float* acc1 = buf + 1 * N_NODES;
        float* acc2 = buf + 2 * N_NODES;
        float* u    = buf + 3 * N_NODES;
        float* w    = out;
        hipMemsetAsync(d_ws, 0, 3 * N_NODES * sizeof(float), stream);
        const int nodeBlocks = (N_NODES + 255) / 256;
        const int edgeBlocks = 2048;
        deg_kernel<<<edgeBlocks, 256, 0, stream>>>(dst, dinv);
        node1_kernel<<<nodeBlocks, 256, 0, stream>>>(x, dinv, u);
        scatter_kernel<<<edgeBlocks, 256, 0, stream>>>(src, dst, u, acc1);
        node2_kernel<<<nodeBlocks, 256, 0, stream>>>(dinv, u, acc1, W1, b1, W2, w);
        scatter_kernel<<<edgeBlocks, 256, 0, stream>>>(src, dst, w, acc2);
        final_kernel<<<nodeBlocks, 256, 0, stream>>>(dinv, w, acc2, b2, out);
    }
}

// Round 14
// 181.891 us; speedup vs baseline: 4.5859x; 1.0522x over previous
//
#include <hip/hip_runtime.h>

#define N_NODES 500000
#define N_EDGES 5000000
#define NB_C 489          // ceil(N_NODES/1024) buckets of 1024 nodes (dst>>10)
#define PB 512            // partition blocks for hist/place
#define EPB 9768          // edges per partition block (mult of 4; PB*EPB >= N_EDGES)
#define SRC_MASK 0xFFFFFu // low 20 bits = src (src < 2^19)

// ===========================================================================
// FAST PATH: zero global atomics. Bucket-sort edges by dst>>10, aggregate in LDS.
// place = LDS counting sort + burst-coalesced run writes (write-combining).
// ===========================================================================

// K1: per-block histogram of dst buckets. hist[block][bin], coalesced row write.
__global__ __launch_bounds__(1024)
void hist_kernel(const int* __restrict__ dst, unsigned* __restrict__ hist) {
    __shared__ unsigned h[NB_C];
    for (int i = threadIdx.x; i < NB_C; i += 1024) h[i] = 0u;
    __syncthreads();
    const int b = blockIdx.x;
    const long s0 = (long)b * EPB;
    const int n = (int)min((long)EPB, (long)N_EDGES - s0);
    const int4* d4 = (const int4*)(dst + s0);
    const int n4 = n >> 2;  // n always a multiple of 4
    for (int i = threadIdx.x; i < n4; i += 1024) {
        int4 d = d4[i];
        atomicAdd(&h[d.x >> 10], 1u);
        atomicAdd(&h[d.y >> 10], 1u);
        atomicAdd(&h[d.z >> 10], 1u);
        atomicAdd(&h[d.w >> 10], 1u);
    }
    __syncthreads();
    unsigned* row = hist + (size_t)b * NB_C;
    for (int i = threadIdx.x; i < NB_C; i += 1024) row[i] = h[i];
}

// K2: per-bin exclusive prefix over the PB block counts (in place) + bin total.
__global__ __launch_bounds__(512)
void prefix_kernel(unsigned* __restrict__ hist, unsigned* __restrict__ binTotal) {
    __shared__ unsigned A[PB], B[PB];
    const int bin = blockIdx.x;
    const int t = threadIdx.x;
    const unsigned c = hist[(size_t)t * NB_C + bin];
    A[t] = c;
    __syncthreads();
    unsigned* cur = A; unsigned* nxt = B;
    for (int off = 1; off < PB; off <<= 1) {
        nxt[t] = cur[t] + (t >= off ? cur[t - off] : 0u);
        __syncthreads();
        unsigned* tmp = cur; cur = nxt; nxt = tmp;
    }
    hist[(size_t)t * NB_C + bin] = cur[t] - c;      // exclusive prefix
    if (t == PB - 1) binTotal[bin] = cur[PB - 1];   // total for this bin
}

// K2b: exclusive scan of the NB_C bin totals -> binStart[0..NB_C].
__global__ __launch_bounds__(512)
void binscan_kernel(const unsigned* __restrict__ binTotal,
                    unsigned* __restrict__ binStart) {
    __shared__ unsigned A[512], B[512];
    const int t = threadIdx.x;
    A[t] = (t < NB_C) ? binTotal[t] : 0u;
    __syncthreads();
    unsigned* cur = A; unsigned* nxt = B;
    for (int off = 1; off < 512; off <<= 1) {
        nxt[t] = cur[t] + (t >= off ? cur[t - off] : 0u);
        __syncthreads();
        unsigned* tmp = cur; cur = nxt; nxt = tmp;
    }
    if (t < NB_C) binStart[t] = (t == 0) ? 0u : cur[t - 1];
    if (t == 0) binStart[NB_C] = cur[NB_C - 1];
}

// K3: LDS counting-sort place. Sort the block's EPB edges by bin in LDS, then
// write each bin-run as one contiguous wave burst -> coalesced full-line writes.
__global__ __launch_bounds__(512)
void place_kernel(const int* __restrict__ src, const int* __restrict__ dst,
                  const unsigned* __restrict__ hist,   // exclusive-prefixed rows
                  const unsigned* __restrict__ binStart,
                  unsigned* __restrict__ edgebuf) {
    __shared__ unsigned lcnt[NB_C];    // block-local bin counts (run lengths)
    __shared__ unsigned lstart[NB_C];  // exclusive scan of lcnt
    __shared__ unsigned gbase[NB_C];   // global write base per bin
    __shared__ unsigned bump[NB_C];    // fill cursors
    __shared__ unsigned scanA[512], scanB[512];
    __shared__ unsigned recs[EPB];     // 39 KB sorted records

    const int b = blockIdx.x;
    const int t = threadIdx.x;
    const unsigned* row = hist + (size_t)b * NB_C;
    for (int i = t; i < NB_C; i += 512) {
        lcnt[i] = 0u;
        bump[i] = 0u;
        gbase[i] = binStart[i] + row[i];
    }
    __syncthreads();
    const long s0 = (long)b * EPB;
    const int n = (int)min((long)EPB, (long)N_EDGES - s0);
    const int4* d4 = (const int4*)(dst + s0);
    const int4* s4 = (const int4*)(src + s0);
    const int n4 = n >> 2;  // n always a multiple of 4
    // pass 1: local histogram
    for (int i = t; i < n4; i += 512) {
        int4 d = d4[i];
        atomicAdd(&lcnt[d.x >> 10], 1u);
        atomicAdd(&lcnt[d.y >> 10], 1u);
        atomicAdd(&lcnt[d.z >> 10], 1u);
        atomicAdd(&lcnt[d.w >> 10], 1u);
    }
    __syncthreads();
    // exclusive scan lcnt -> lstart
    scanA[t] = (t < NB_C) ? lcnt[t] : 0u;
    __syncthreads();
    unsigned* cur = scanA; unsigned* nxt = scanB;
    for (int off = 1; off < 512; off <<= 1) {
        nxt[t] = cur[t] + (t >= off ? cur[t - off] : 0u);
        __syncthreads();
        unsigned* tmp = cur; cur = nxt; nxt = tmp;
    }
    if (t < NB_C) lstart[t] = cur[t] - lcnt[t];
    __syncthreads();
    // pass 2: fill sorted LDS records (dst slice re-read is L1/L2-hot)
    for (int i = t; i < n4; i += 512) {
        int4 s = s4[i];
        int4 d = d4[i];
        unsigned bin, pos;
        bin = (unsigned)d.x >> 10;
        pos = lstart[bin] + atomicAdd(&bump[bin], 1u);
        recs[pos] = ((unsigned)(d.x & 1023) << 20) | (unsigned)s.x;
        bin = (unsigned)d.y >> 10;
        pos = lstart[bin] + atomicAdd(&bump[bin], 1u);
        recs[pos] = ((unsigned)(d.y & 1023) << 20) | (unsigned)s.y;
        bin = (unsigned)d.z >> 10;
        pos = lstart[bin] + atomicAdd(&bump[bin], 1u);
        recs[pos] = ((unsigned)(d.z & 1023) << 20) | (unsigned)s.z;
        bin = (unsigned)d.w >> 10;
        pos = lstart[bin] + atomicAdd(&bump[bin], 1u);
        recs[pos] = ((unsigned)(d.w & 1023) << 20) | (unsigned)s.w;
    }
    __syncthreads();
    // pass 3: burst-copy each bin run (wave per bin, contiguous lanes)
    const int wave = t >> 6;
    const int lane = t & 63;
    for (int bin = wave; bin < NB_C; bin += 8) {
        const unsigned L  = lcnt[bin];
        const unsigned gs = gbase[bin];
        const unsigned ls = lstart[bin];
        for (unsigned i = lane; i < L; i += 64)
            edgebuf[gs + i] = recs[ls + i];
    }
}

// K4a: per-bucket in-degree -> dinv = rsqrt(deg+1); u = x*dinv. (node1 fused)
__global__ __launch_bounds__(1024)
void deg_dinv_kernel(const unsigned* __restrict__ edgebuf,
                     const unsigned* __restrict__ binStart,
                     const float* __restrict__ x,
                     float* __restrict__ dinv, float* __restrict__ u) {
    __shared__ unsigned cnt[1024];
    cnt[threadIdx.x] = 0u;
    __syncthreads();
    const int bin = blockIdx.x;
    const unsigned e0 = binStart[bin], e1 = binStart[bin + 1];
    const unsigned ea = (e0 + 3u) & ~3u;
    const unsigned eb = e1 & ~3u;
    for (unsigned e = e0 + threadIdx.x; e < min(ea, e1); e += 1024)
        atomicAdd(&cnt[edgebuf[e] >> 20], 1u);
    if (ea < eb) {
        const uint4* p4 = (const uint4*)(edgebuf + ea);
        const unsigned nv = (eb - ea) >> 2;
        for (unsigned i = threadIdx.x; i < nv; i += 1024) {
            uint4 r = p4[i];
            atomicAdd(&cnt[r.x >> 20], 1u);
            atomicAdd(&cnt[r.y >> 20], 1u);
            atomicAdd(&cnt[r.z >> 20], 1u);
            atomicAdd(&cnt[r.w >> 20], 1u);
        }
    }
    for (unsigned e = max(eb, min(ea, e1)) + threadIdx.x; e < e1; e += 1024)
        atomicAdd(&cnt[edgebuf[e] >> 20], 1u);
    __syncthreads();
    const int node = (bin << 10) + threadIdx.x;
    if (node < N_NODES) {
        float di = rsqrtf((float)cnt[threadIdx.x] + 1.0f);
        dinv[node] = di;
        u[node] = x[node] * di;
    }
}

// K4b: agg1 (sum u[src] per node, LDS) + collapsed 16-wide MLP -> w. (node2 fused)
__global__ __launch_bounds__(1024)
void agg1_kernel(const unsigned* __restrict__ edgebuf,
                 const unsigned* __restrict__ binStart,
                 const float* __restrict__ dinv, const float* __restrict__ u,
                 const float* __restrict__ W1, const float* __restrict__ b1,
                 const float* __restrict__ W2, float* __restrict__ w) {
    __shared__ float sum[1024];
    sum[threadIdx.x] = 0.0f;
    __syncthreads();
    const int bin = blockIdx.x;
    const unsigned e0 = binStart[bin], e1 = binStart[bin + 1];
    const unsigned ea = (e0 + 3u) & ~3u;
    const unsigned eb = e1 & ~3u;
    for (unsigned e = e0 + threadIdx.x; e < min(ea, e1); e += 1024) {
        unsigned rec = edgebuf[e];
        atomicAdd(&sum[rec >> 20], u[rec & SRC_MASK]);
    }
    if (ea < eb) {
        const uint4* p4 = (const uint4*)(edgebuf + ea);
        const unsigned nv = (eb - ea) >> 2;
        for (unsigned i = threadIdx.x; i < nv; i += 1024) {
            uint4 r = p4[i];
            atomicAdd(&sum[r.x >> 20], u[r.x & SRC_MASK]);
            atomicAdd(&sum[r.y >> 20], u[r.y & SRC_MASK]);
            atomicAdd(&sum[r.z >> 20], u[r.z & SRC_MASK]);
            atomicAdd(&sum[r.w >> 20], u[r.w & SRC_MASK]);
        }
    }
    for (unsigned e = max(eb, min(ea, e1)) + threadIdx.x; e < e1; e += 1024) {
        unsigned rec = edgebuf[e];
        atomicAdd(&sum[rec >> 20], u[rec & SRC_MASK]);
    }
    __syncthreads();
    const int node = (bin << 10) + threadIdx.x;
    if (node < N_NODES) {
        float di = dinv[node];
        float s = di * (sum[threadIdx.x] + u[node]);
        float t = 0.0f;
#pragma unroll
        for (int j = 0; j < 16; ++j) {
            float h = fmaf(W1[j], s, b1[j]);
            h = fmaxf(h, 0.0f);
            t = fmaf(h, W2[j], t);
        }
        w[node] = t * di;
    }
}

// K4c: agg2 (sum w[src] per node, LDS) + final epilogue -> out.
__global__ __launch_bounds__(1024)
void agg2_kernel(const unsigned* __restrict__ edgebuf,
                 const unsigned* __restrict__ binStart,
                 const float* __restrict__ dinv, const float* __restrict__ w,
                 const float* __restrict__ b2, float* __restrict__ out) {
    __shared__ float sum[1024];
    sum[threadIdx.x] = 0.0f;
    __syncthreads();
    const int bin = blockIdx.x;
    const unsigned e0 = binStart[bin], e1 = binStart[bin + 1];
    const unsigned ea = (e0 + 3u) & ~3u;
    const unsigned eb = e1 & ~3u;
    for (unsigned e = e0 + threadIdx.x; e < min(ea, e1); e += 1024) {
        unsigned rec = edgebuf[e];
        atomicAdd(&sum[rec >> 20], w[rec & SRC_MASK]);
    }
    if (ea < eb) {
        const uint4* p4 = (const uint4*)(edgebuf + ea);
        const unsigned nv = (eb - ea) >> 2;
        for (unsigned i = threadIdx.x; i < nv; i += 1024) {
            uint4 r = p4[i];
            atomicAdd(&sum[r.x >> 20], w[r.x & SRC_MASK]);
            atomicAdd(&sum[r.y >> 20], w[r.y & SRC_MASK]);
            atomicAdd(&sum[r.z >> 20], w[r.z & SRC_MASK]);
            atomicAdd(&sum[r.w >> 20], w[r.w & SRC_MASK]);
        }
    }
    for (unsigned e = max(eb, min(ea, e1)) + threadIdx.x; e < e1; e += 1024) {
        unsigned rec = edgebuf[e];
        atomicAdd(&sum[rec >> 20], w[rec & SRC_MASK]);
    }
    __syncthreads();
    const int node = (bin << 10) + threadIdx.x;
    if (node < N_NODES)
        out[node] = fmaf(dinv[node], sum[threadIdx.x] + w[node], b2[0]);
}

// ===========================================================================
// FALLBACK PATH (verified round-4 kernels) — used only if ws_size is too small.
// ===========================================================================
__global__ __launch_bounds__(256)
void deg_kernel(const int* __restrict__ dst, float* __restrict__ deg) {
    const int tid = blockIdx.x * blockDim.x + threadIdx.x;
    const int stride = gridDim.x * blockDim.x;
    const int nvec = N_EDGES / 4;
    const int4* dst4 = (const int4*)dst;
    for (int i = tid; i < nvec; i += stride) {
        int4 d = dst4[i];
        atomicAdd(&deg[d.x], 1.0f);
        atomicAdd(&deg[d.y], 1.0f);
        atomicAdd(&deg[d.z], 1.0f);
        atomicAdd(&deg[d.w], 1.0f);
    }
}
__global__ __launch_bounds__(256)
void node1_kernel(const float* __restrict__ x, float* __restrict__ deg_to_dinv,
                  float* __restrict__ u) {
    const int i = blockIdx.x * blockDim.x + threadIdx.x;
    if (i >= N_NODES) return;
    float di = rsqrtf(deg_to_dinv[i] + 1.0f);
    deg_to_dinv[i] = di;
    u[i] = x[i] * di;
}
__global__ __launch_bounds__(256)
void scatter_kernel(const int* __restrict__ src, const int* __restrict__ dst,
                    const float* __restrict__ val, float* __restrict__ acc) {
    const int tid = blockIdx.x * blockDim.x + threadIdx.x;
    const int stride = gridDim.x * blockDim.x;
    const int nvec = N_EDGES / 4;
    const int4* src4 = (const int4*)src;
    const int4* dst4 = (const int4*)dst;
    for (int i = tid; i < nvec; i += stride) {
        int4 s = src4[i];
        int4 d = dst4[i];
        atomicAdd(&acc[d.x], val[s.x]);
        atomicAdd(&acc[d.y], val[s.y]);
        atomicAdd(&acc[d.z], val[s.z]);
        atomicAdd(&acc[d.w], val[s.w]);
    }
}
__global__ __launch_bounds__(256)
void node2_kernel(const float* __restrict__ dinv, const float* __restrict__ u,
                  const float* __restrict__ acc1, const float* __restrict__ W1,
                  const float* __restrict__ b1, const float* __restrict__ W2,
                  float* __restrict__ w) {
    const int i = blockIdx.x * blockDim.x + threadIdx.x;
    if (i >= N_NODES) return;
    float di = dinv[i];
    float s = di * (acc1[i] + u[i]);
    float t = 0.0f;
#pragma unroll
    for (int j = 0; j < 16; ++j) {
        float h = fmaf(W1[j], s, b1[j]);
        h = fmaxf(h, 0.0f);
        t = fmaf(h, W2[j], t);
    }
    w[i] = t * di;
}
__global__ __launch_bounds__(256)
void final_kernel(const float* __restrict__ dinv, const float* __restrict__ w,
                  const float* __restrict__ acc2, const float* __restrict__ b2,
                  float* __restrict__ out) {
    const int i = blockIdx.x * blockDim.x + threadIdx.x;
    if (i >= N_NODES) return;
    float wi = w[i];
    out[i] = fmaf(dinv[i], acc2[i] + wi, b2[0]);
}

// ===========================================================================
extern "C" void kernel_launch(void* const* d_in, const int* in_sizes, int n_in,
                              void* d_out, int out_size, void* d_ws, size_t ws_size,
                              hipStream_t stream) {
    const float* x  = (const float*)d_in[0];
    const float* W1 = (const float*)d_in[1];
    const float* b1 = (const float*)d_in[2];
    const float* W2 = (const float*)d_in[3];
    const float* b2 = (const float*)d_in[4];
    const int* edge_index = (const int*)d_in[5];
    const int* src = edge_index;
    const int* dst = edge_index + N_EDGES;
    float* out = (float*)d_out;
    char* ws = (char*)d_ws;

    // Fast-path workspace layout (byte offsets, 16B-aligned):
    const size_t OFF_EDGEBUF  = 0;                    // u32[N_EDGES]  20,000,000
    const size_t OFF_HIST     = 20000000;             // u32[PB*NB_C]   1,001,472
    const size_t OFF_BINSTART = 21001472;             // u32[NB_C+1]        1,960
    const size_t OFF_BINTOTAL = 21003440;             // u32[NB_C]          1,956
    const size_t OFF_DINV     = 21005408;             // f32[N]
    const size_t OFF_U        = OFF_DINV + 2000000;
    const size_t OFF_W        = OFF_U + 2000000;
    const size_t FAST_WS      = OFF_W + 2000000;      // ~27.0 MB

    if (ws_size >= FAST_WS) {
        unsigned* edgebuf  = (unsigned*)(ws + OFF_EDGEBUF);
        unsigned* hist     = (unsigned*)(ws + OFF_HIST);
        unsigned* binStart = (unsigned*)(ws + OFF_BINSTART);
        unsigned* binTotal = (unsigned*)(ws + OFF_BINTOTAL);
        float* dinv = (float*)(ws + OFF_DINV);
        float* u    = (float*)(ws + OFF_U);
        float* w    = (float*)(ws + OFF_W);

        hist_kernel<<<PB, 1024, 0, stream>>>(dst, hist);
        prefix_kernel<<<NB_C, PB, 0, stream>>>(hist, binTotal);
        binscan_kernel<<<1, 512, 0, stream>>>(binTotal, binStart);
        place_kernel<<<PB, 512, 0, stream>>>(src, dst, hist, binStart, edgebuf);
        deg_dinv_kernel<<<NB_C, 1024, 0, stream>>>(edgebuf, binStart, x, dinv, u);
        agg1_kernel<<<NB_C, 1024, 0, stream>>>(edgebuf, binStart, dinv, u, W1, b1, W2, w);
        agg2_kernel<<<NB_C, 1024, 0, stream>>>(edgebuf, binStart, dinv, w, b2, out);
    } else {
        // Fallback: verified global-atomic path.
        float* buf  = (float*)d_ws;
        float* dinv = buf;
        float* acc1 = buf + 1 * N_NODES;
        float* acc2 = buf + 2 * N_NODES;
        float* u    = buf + 3 * N_NODES;
        float* w    = out;
        hipMemsetAsync(d_ws, 0, 3 * N_NODES * sizeof(float), stream);
        const int nodeBlocks = (N_NODES + 255) / 256;
        const int edgeBlocks = 2048;
        deg_kernel<<<edgeBlocks, 256, 0, stream>>>(dst, dinv);
        node1_kernel<<<nodeBlocks, 256, 0, stream>>>(x, dinv, u);
        scatter_kernel<<<edgeBlocks, 256, 0, stream>>>(src, dst, u, acc1);
        node2_kernel<<<nodeBlocks, 256, 0, stream>>>(dinv, u, acc1, W1, b1, W2, w);
        scatter_kernel<<<edgeBlocks, 256, 0, stream>>>(src, dst, w, acc2);
        final_kernel<<<nodeBlocks, 256, 0, stream>>>(dinv, w, acc2, b2, out);
    }
}